// Round 1
// baseline (10860.644 us; speedup 1.0000x reference)
//
#include <hip/hip_runtime.h>
#include <math.h>

#define NN 100000
#define HH 512
#define KK 128
#define BETA 100.0f
#define EPSF 1e-8f
#define ITERS 11

__device__ __forceinline__ float wave_reduce_sum(float v) {
#pragma unroll
  for (int off = 32; off > 0; off >>= 1) v += __shfl_xor(v, off);
  return v;
}
__device__ __forceinline__ float wave_reduce_max(float v) {
#pragma unroll
  for (int off = 32; off > 0; off >>= 1) v = fmaxf(v, __shfl_xor(v, off));
  return v;
}
__device__ __forceinline__ float softplusf(float x) {
  return fmaxf(x, 0.0f) + log1pf(expf(-fabsf(x)));
}

// ---- prep: inv_norm[i] = 1/(||pos_i||+eps); colsum[h] = sum_i pos[i][h]
__global__ void prep_kernel(const float* __restrict__ pos,
                            float* __restrict__ inv_norm,
                            float* __restrict__ colsum) {
  int w = threadIdx.x >> 6, lane = threadIdx.x & 63;
  int gw = blockIdx.x * 4 + w;  // 0..1023
  float cpart[8] = {0, 0, 0, 0, 0, 0, 0, 0};
  for (int row = gw; row < NN; row += 1024) {
    const float* p = pos + (size_t)row * HH;
    float ss = 0.f;
#pragma unroll
    for (int j = 0; j < 8; ++j) {
      float v = p[lane + 64 * j];
      ss += v * v;
      cpart[j] += v;
    }
    ss = wave_reduce_sum(ss);
    if (lane == 0) inv_norm[row] = 1.0f / (sqrtf(ss) + EPSF);
  }
  __shared__ float cs[HH];
  cs[threadIdx.x] = 0.f;
  cs[threadIdx.x + 256] = 0.f;
  __syncthreads();
#pragma unroll
  for (int j = 0; j < 8; ++j) atomicAdd(&cs[lane + 64 * j], cpart[j]);
  __syncthreads();
  atomicAdd(&colsum[threadIdx.x], cs[threadIdx.x]);
  atomicAdd(&colsum[threadIdx.x + 256], cs[threadIdx.x + 256]);
}

// ---- gs[h] = sigmoid(colsum[h]/N)
__global__ void gs_kernel(const float* __restrict__ colsum, float* __restrict__ gs) {
  int t = threadIdx.x;  // 512 threads
  float m = colsum[t] * (1.0f / NN);
  gs[t] = 1.0f / (1.0f + expf(-m));
}

// ---- Ws[j] = sum_h W[j][h]*gs[h]
__global__ void wsum_kernel(const float* __restrict__ W, const float* __restrict__ gs,
                            float* __restrict__ Ws) {
  int w = threadIdx.x >> 6, lane = threadIdx.x & 63;
  int row = blockIdx.x * 4 + w;
  const float* Wr = W + (size_t)row * HH;
  float s = 0.f;
#pragma unroll
  for (int j = 0; j < 8; ++j) s += Wr[lane + 64 * j] * gs[lane + 64 * j];
  s = wave_reduce_sum(s);
  if (lane == 0) Ws[row] = s;
}

// ---- mu_norm = mu / ||mu|| (rowwise, no eps); zero cluster_r
__global__ void norm_mu_kernel(const float* __restrict__ mu, float* __restrict__ mu_norm,
                               float* __restrict__ cluster_r) {
  int k = blockIdx.x, t = threadIdx.x;
  float v0 = mu[k * HH + t], v1 = mu[k * HH + t + 256];
  float ss = v0 * v0 + v1 * v1;
  ss = wave_reduce_sum(ss);
  __shared__ float red[4];
  if ((t & 63) == 0) red[t >> 6] = ss;
  __syncthreads();
  float tot = red[0] + red[1] + red[2] + red[3];
  float inv = 1.0f / sqrtf(tot);
  mu_norm[k * HH + t] = v0 * inv;
  mu_norm[k * HH + t + 256] = v1 * inv;
  if (t == 0) cluster_r[k] = 0.f;
}

// ---- dist tile (64 rows x 128 clusters) + row softmax -> r_buf
__launch_bounds__(256)
__global__ void dist_kernel(const float* __restrict__ pos, const float* __restrict__ inv_norm,
                            const float* __restrict__ mu_norm, float* __restrict__ r_buf) {
  __shared__ float As[64][33];
  __shared__ float Bs[KK][33];
  __shared__ float distS[64][KK];
  __shared__ float invS[64];
  int t = threadIdx.x;
  int i0 = blockIdx.x * 64;
  if (t < 64) {
    int gi = i0 + t;
    invS[t] = (gi < NN) ? inv_norm[gi] : 0.f;
  }
  int kk = t & 31, ra = t >> 5;  // ra 0..7
  int ty = t >> 4, tx = t & 15;
  float acc[4][8];
#pragma unroll
  for (int x = 0; x < 4; ++x)
#pragma unroll
    for (int y = 0; y < 8; ++y) acc[x][y] = 0.f;

  for (int ch = 0; ch < HH / 32; ++ch) {
    int h0 = ch * 32;
    __syncthreads();
#pragma unroll
    for (int j = 0; j < 8; ++j) {
      int row = ra + 8 * j;
      int gi = i0 + row;
      As[row][kk] = (gi < NN) ? pos[(size_t)gi * HH + h0 + kk] * invS[row] : 0.f;
    }
#pragma unroll
    for (int j = 0; j < 16; ++j) {
      int c = ra + 8 * j;
      Bs[c][kk] = mu_norm[c * HH + h0 + kk];
    }
    __syncthreads();
#pragma unroll
    for (int q = 0; q < 32; ++q) {
      float a[4], b[8];
#pragma unroll
      for (int x = 0; x < 4; ++x) a[x] = As[ty * 4 + x][q];
#pragma unroll
      for (int y = 0; y < 8; ++y) b[y] = Bs[tx + 16 * y][q];
#pragma unroll
      for (int x = 0; x < 4; ++x)
#pragma unroll
        for (int y = 0; y < 8; ++y) acc[x][y] += a[x] * b[y];
    }
  }
  __syncthreads();
#pragma unroll
  for (int x = 0; x < 4; ++x)
#pragma unroll
    for (int y = 0; y < 8; ++y) distS[ty * 4 + x][tx + 16 * y] = acc[x][y];
  __syncthreads();

  int w = t >> 6, lane = t & 63;
  for (int row = w; row < 64; row += 4) {
    int gi = i0 + row;
    float d0 = distS[row][lane] * BETA;
    float d1 = distS[row][lane + 64] * BETA;
    float m = fmaxf(d0, d1);
    m = wave_reduce_max(m);
    float e0 = expf(d0 - m), e1 = expf(d1 - m);
    float s = e0 + e1;
    s = wave_reduce_sum(s);
    float inv = 1.0f / s;
    if (gi < NN) {
      r_buf[(size_t)gi * KK + lane] = e0 * inv;
      r_buf[(size_t)gi * KK + lane + 64] = e1 * inv;
    }
  }
}

// ---- muN[k][h] += sum_i r[i][k]*data[i][h]; cluster_r[k] += sum_i r[i][k]
__launch_bounds__(256)
__global__ void muup_kernel(const float* __restrict__ r_buf, const float* __restrict__ pos,
                            const float* __restrict__ inv_norm, float* __restrict__ muN,
                            float* __restrict__ cluster_r) {
  __shared__ float Rt[32][KK];
  __shared__ float Dt[32][KK];
  int t = threadIdx.x;
  int ht = blockIdx.x;  // 0..3 (h tile of 128)
  int s = blockIdx.y;
  int S = gridDim.y;
  int k = t & 127, half = t >> 7;
  int ty = t >> 4, tx = t & 15;
  float acc[8][8];
#pragma unroll
  for (int x = 0; x < 8; ++x)
#pragma unroll
    for (int y = 0; y < 8; ++y) acc[x][y] = 0.f;
  float cpart = 0.f;

  for (int c = s; c < NN / 32; c += S) {
    int ibase = c * 32;
    __syncthreads();
#pragma unroll
    for (int j = 0; j < 16; ++j) {
      int ii = half + 2 * j;
      int gi = ibase + ii;
      float rv = r_buf[(size_t)gi * KK + k];
      if (ht == 0) cpart += rv;
      Rt[ii][k] = rv;
      Dt[ii][k] = pos[(size_t)gi * HH + ht * 128 + k] * inv_norm[gi];
    }
    __syncthreads();
#pragma unroll
    for (int ii = 0; ii < 32; ++ii) {
      float a[8], b[8];
#pragma unroll
      for (int x = 0; x < 8; ++x) a[x] = Rt[ii][ty * 8 + x];
#pragma unroll
      for (int y = 0; y < 8; ++y) b[y] = Dt[ii][tx + 16 * y];
#pragma unroll
      for (int x = 0; x < 8; ++x)
#pragma unroll
        for (int y = 0; y < 8; ++y) acc[x][y] += a[x] * b[y];
    }
  }
#pragma unroll
  for (int x = 0; x < 8; ++x)
#pragma unroll
    for (int y = 0; y < 8; ++y)
      atomicAdd(&muN[(ty * 8 + x) * HH + ht * 128 + tx + 16 * y], acc[x][y]);
  if (ht == 0) atomicAdd(&cluster_r[k], cpart);
}

// ---- mu = muN / cluster_r
__global__ void fin_mu_kernel(const float* __restrict__ muN, const float* __restrict__ cluster_r,
                              float* __restrict__ mu) {
  int k = blockIdx.x, t = threadIdx.x;
  float inv = 1.0f / cluster_r[k];
  mu[k * HH + t] = muN[k * HH + t] * inv;
  mu[k * HH + t + 256] = muN[k * HH + t + 256] * inv;
}

// ---- fused loss: cs = sigmoid(r@mu); dots with pos/neg/Ws; softplus; accumulate
__launch_bounds__(256)
__global__ void loss_kernel(const float* __restrict__ r_buf, const float* __restrict__ mu,
                            const float* __restrict__ pos, const float* __restrict__ neg,
                            const float* __restrict__ Wsv, float* __restrict__ loss_accum) {
  __shared__ float rS[16][KK];
  __shared__ float pgS[16], ngS[16], pcS[16], ncS[16];
  int t = threadIdx.x;
  int i0 = blockIdx.x * 16;
  int k = t & 127, half = t >> 7;
#pragma unroll
  for (int j = 0; j < 8; ++j) {
    int rr = half + 2 * j;
    rS[rr][k] = r_buf[(size_t)(i0 + rr) * KK + k];
  }
  if (t < 16) {
    pgS[t] = 0.f; ngS[t] = 0.f; pcS[t] = 0.f; ncS[t] = 0.f;
  }
  __syncthreads();
  float w0 = Wsv[t], w1 = Wsv[t + 256];
  float cs0[16], cs1[16];
#pragma unroll
  for (int rr = 0; rr < 16; ++rr) { cs0[rr] = 0.f; cs1[rr] = 0.f; }
  for (int kq = 0; kq < KK; ++kq) {
    float m0 = mu[kq * HH + t];
    float m1 = mu[kq * HH + t + 256];
#pragma unroll
    for (int rr = 0; rr < 16; ++rr) {
      float rv = rS[rr][kq];
      cs0[rr] += rv * m0;
      cs1[rr] += rv * m1;
    }
  }
  int lane = t & 63;
  for (int rr = 0; rr < 16; ++rr) {
    float s0 = 1.0f / (1.0f + expf(-cs0[rr]));
    float s1 = 1.0f / (1.0f + expf(-cs1[rr]));
    const float* pr = pos + (size_t)(i0 + rr) * HH;
    const float* nr = neg + (size_t)(i0 + rr) * HH;
    float p0 = pr[t], p1 = pr[t + 256];
    float n0 = nr[t], n1 = nr[t + 256];
    float pc = p0 * s0 + p1 * s1;
    float nc = n0 * s0 + n1 * s1;
    float pg = p0 * w0 + p1 * w1;
    float ng = n0 * w0 + n1 * w1;
    pc = wave_reduce_sum(pc);
    nc = wave_reduce_sum(nc);
    pg = wave_reduce_sum(pg);
    ng = wave_reduce_sum(ng);
    if (lane == 0) {
      atomicAdd(&pcS[rr], pc);
      atomicAdd(&ncS[rr], nc);
      atomicAdd(&pgS[rr], pg);
      atomicAdd(&ngS[rr], ng);
    }
  }
  __syncthreads();
  if (t < 64) {
    float contrib = 0.f;
    if (t < 16) {
      float pg = pgS[t], ng = ngS[t], pc = pcS[t], nc = ncS[t];
      contrib = 0.5f * (softplusf(-pg) + softplusf(ng)) +
                0.5f * (softplusf(-pc) + softplusf(nc));
    }
    contrib = wave_reduce_sum(contrib);
    if (t == 0) atomicAdd(loss_accum, contrib);
  }
}

__global__ void out_kernel(const float* __restrict__ loss_accum, float* __restrict__ out) {
  out[0] = loss_accum[0] * (1.0f / NN);
}

extern "C" void kernel_launch(void* const* d_in, const int* in_sizes, int n_in,
                              void* d_out, int out_size, void* d_ws, size_t ws_size,
                              hipStream_t stream) {
  const float* pos = (const float*)d_in[0];
  const float* neg = (const float*)d_in[1];
  const float* init = (const float*)d_in[2];
  const float* W = (const float*)d_in[3];
  float* out = (float*)d_out;

  char* ws = (char*)d_ws;
  size_t off = 0;
  auto alloc = [&](size_t nfloats) {
    float* p = (float*)(ws + off);
    off += nfloats * sizeof(float);
    return p;
  };
  float* r_buf = alloc((size_t)NN * KK);   // 51.2 MB
  float* inv_norm = alloc(NN);             // 400 KB
  float* mu = alloc(KK * HH);
  float* mu_norm = alloc(KK * HH);
  float* muN = alloc(KK * HH);
  float* cluster_r = alloc(KK);
  float* colsum = alloc(HH);
  float* gs = alloc(HH);
  float* Ws = alloc(HH);
  float* loss_accum = alloc(4);

  hipMemsetAsync(colsum, 0, HH * sizeof(float), stream);
  hipMemsetAsync(loss_accum, 0, sizeof(float), stream);
  hipMemcpyAsync(mu, init, (size_t)KK * HH * sizeof(float), hipMemcpyDeviceToDevice, stream);

  prep_kernel<<<256, 256, 0, stream>>>(pos, inv_norm, colsum);
  gs_kernel<<<1, 512, 0, stream>>>(colsum, gs);
  wsum_kernel<<<128, 256, 0, stream>>>(W, gs, Ws);

  for (int it = 0; it < ITERS; ++it) {
    norm_mu_kernel<<<128, 256, 0, stream>>>(mu, mu_norm, cluster_r);
    dist_kernel<<<(NN + 63) / 64, 256, 0, stream>>>(pos, inv_norm, mu_norm, r_buf);
    hipMemsetAsync(muN, 0, (size_t)KK * HH * sizeof(float), stream);
    muup_kernel<<<dim3(4, 64), 256, 0, stream>>>(r_buf, pos, inv_norm, muN, cluster_r);
    fin_mu_kernel<<<128, 256, 0, stream>>>(muN, cluster_r, mu);
  }

  loss_kernel<<<NN / 16, 256, 0, stream>>>(r_buf, mu, pos, neg, Ws, loss_accum);
  out_kernel<<<1, 1, 0, stream>>>(loss_accum, out);
}

// Round 2
// 1824.247 us; speedup vs baseline: 5.9535x; 5.9535x over previous
//
#include <hip/hip_runtime.h>
#include <math.h>

#define NN 100000
#define PADN 100096    // 782*128
#define NBLK 782
#define HH 512
#define KK 128
#define BETA 100.0f
#define EPSF 1e-8f
#define ITERS 11
#define NSPLIT 128
#define NCHUNK (PADN / 64)  // 1564

typedef __attribute__((ext_vector_type(8))) short short8v;
typedef __attribute__((ext_vector_type(4))) float float4v;

typedef const __attribute__((address_space(1))) void* gas_t;
typedef __attribute__((address_space(3))) void* las_t;

__device__ __forceinline__ void gload16(const void* g, void* l) {
  __builtin_amdgcn_global_load_lds((gas_t)g, (las_t)l, 16, 0, 0);
}

__device__ __forceinline__ unsigned short f2bf(float x) {
  unsigned int u = __float_as_uint(x);
  unsigned int r = (u + 0x7fff + ((u >> 16) & 1)) >> 16;
  return (unsigned short)r;
}
__device__ __forceinline__ float bf2f(unsigned short b) {
  return __uint_as_float((unsigned int)b << 16);
}

__device__ __forceinline__ float wave_reduce_sum(float v) {
#pragma unroll
  for (int off = 32; off > 0; off >>= 1) v += __shfl_xor(v, off);
  return v;
}
__device__ __forceinline__ float softplusf(float x) {
  return fmaxf(x, 0.0f) + log1pf(expf(-fabsf(x)));
}

// ---- prep: inv_norm[i] = 1/(||pos_i||+eps); colsum[h] = sum_i pos[i][h]
__global__ void prep_kernel(const float* __restrict__ pos,
                            float* __restrict__ inv_norm,
                            float* __restrict__ colsum) {
  int w = threadIdx.x >> 6, lane = threadIdx.x & 63;
  int gw = blockIdx.x * 4 + w;
  float cpart[8] = {0, 0, 0, 0, 0, 0, 0, 0};
  for (int row = gw; row < NN; row += 1024) {
    const float* p = pos + (size_t)row * HH;
    float ss = 0.f;
#pragma unroll
    for (int j = 0; j < 8; ++j) {
      float v = p[lane + 64 * j];
      ss += v * v;
      cpart[j] += v;
    }
    ss = wave_reduce_sum(ss);
    if (lane == 0) inv_norm[row] = 1.0f / (sqrtf(ss) + EPSF);
  }
  __shared__ float cs[HH];
  cs[threadIdx.x] = 0.f;
  cs[threadIdx.x + 256] = 0.f;
  __syncthreads();
#pragma unroll
  for (int j = 0; j < 8; ++j) atomicAdd(&cs[lane + 64 * j], cpart[j]);
  __syncthreads();
  atomicAdd(&colsum[threadIdx.x], cs[threadIdx.x]);
  atomicAdd(&colsum[threadIdx.x + 256], cs[threadIdx.x + 256]);
}

// ---- one-time: normalized bf16 copies of pos: row-major (posb) + transposed (posbT)
__launch_bounds__(256)
__global__ void convert_kernel(const float* __restrict__ pos, const float* __restrict__ inv_norm,
                               unsigned short* __restrict__ posb, unsigned short* __restrict__ posbT) {
  __shared__ unsigned short tile[64][72];
  int t = threadIdx.x;
  int i0 = blockIdx.x * 64, h0 = blockIdx.y * 64;
  int r = t >> 2, cg = (t & 3) * 16;
  int gi = i0 + r;
  bool valid = gi < NN;
  float inv = valid ? inv_norm[gi] : 0.f;
  unsigned short v16[16];
#pragma unroll
  for (int q = 0; q < 4; ++q) {
    float4 f;
    if (valid) f = *(const float4*)&pos[(size_t)gi * HH + h0 + cg + q * 4];
    else { f.x = 0.f; f.y = 0.f; f.z = 0.f; f.w = 0.f; }
    v16[q * 4 + 0] = f2bf(f.x * inv);
    v16[q * 4 + 1] = f2bf(f.y * inv);
    v16[q * 4 + 2] = f2bf(f.z * inv);
    v16[q * 4 + 3] = f2bf(f.w * inv);
  }
#pragma unroll
  for (int q = 0; q < 2; ++q) {
    short8v o;
#pragma unroll
    for (int e = 0; e < 8; ++e) o[e] = (short)v16[q * 8 + e];
    *(short8v*)&posb[(size_t)gi * HH + h0 + cg + q * 8] = o;
  }
#pragma unroll
  for (int q = 0; q < 16; ++q) tile[cg + q][r] = v16[q];
  __syncthreads();
  int h = t >> 2, ig = (t & 3) * 16;
#pragma unroll
  for (int q = 0; q < 2; ++q)
    *(short8v*)&posbT[(size_t)(h0 + h) * PADN + i0 + ig + q * 8] =
        *(const short8v*)&tile[h][ig + q * 8];
}

// ---- gs[h] = sigmoid(colsum[h]/N)
__global__ void gs_kernel(const float* __restrict__ colsum, float* __restrict__ gs) {
  int t = threadIdx.x;
  float m = colsum[t] * (1.0f / NN);
  gs[t] = 1.0f / (1.0f + expf(-m));
}

// ---- Ws[j] = sum_h W[j][h]*gs[h]
__global__ void wsum_kernel(const float* __restrict__ W, const float* __restrict__ gs,
                            float* __restrict__ Ws) {
  int w = threadIdx.x >> 6, lane = threadIdx.x & 63;
  int row = blockIdx.x * 4 + w;
  const float* Wr = W + (size_t)row * HH;
  float s = 0.f;
#pragma unroll
  for (int j = 0; j < 8; ++j) s += Wr[lane + 64 * j] * gs[lane + 64 * j];
  s = wave_reduce_sum(s);
  if (lane == 0) Ws[row] = s;
}

// ---- mu_norm (bf16) = mu / ||mu||; zero cluster_r
__global__ void norm_mu_kernel(const float* __restrict__ mu, unsigned short* __restrict__ mub,
                               float* __restrict__ cluster_r) {
  int k = blockIdx.x, t = threadIdx.x;
  float v0 = mu[k * HH + t], v1 = mu[k * HH + t + 256];
  float ss = v0 * v0 + v1 * v1;
  ss = wave_reduce_sum(ss);
  __shared__ float red[4];
  if ((t & 63) == 0) red[t >> 6] = ss;
  __syncthreads();
  float inv = 1.0f / sqrtf(red[0] + red[1] + red[2] + red[3]);
  mub[k * HH + t] = f2bf(v0 * inv);
  mub[k * HH + t + 256] = f2bf(v1 * inv);
  if (t == 0) cluster_r[k] = 0.f;
}

// ---- MFMA dist + fused softmax: writes rbfT (always), rbf (flag), cluster_r (fp32 exact)
__launch_bounds__(256, 2)
__global__ void dist_mfma(const unsigned short* __restrict__ posb,
                          const unsigned short* __restrict__ mub,
                          unsigned short* __restrict__ rbf,
                          unsigned short* __restrict__ rbfT,
                          float* __restrict__ cluster_r,
                          int write_rbf) {
  __shared__ unsigned short As[2][8192];  // [row 128][col 64] bf16
  __shared__ unsigned short Bs[2][8192];
  __shared__ float redM[2][128];
  __shared__ float redS[2][128];
  unsigned short* rT = (unsigned short*)&As[0][0];  // [128 c][136] aliased in epilogue

  int t = threadIdx.x;
  int w = t >> 6, l = t & 63;
  int wr = w >> 1, wc = w & 1;
  int i0 = blockIdx.x * 128;

  float4v acc[4][4];
#pragma unroll
  for (int mi = 0; mi < 4; ++mi)
#pragma unroll
    for (int ni = 0; ni < 4; ++ni) acc[mi][ni] = (float4v){0.f, 0.f, 0.f, 0.f};

  auto stage = [&](int buf, int ch) {
    int h0 = ch * 64;
#pragma unroll
    for (int j = 0; j < 4; ++j) {
      int v = w * 4 + j;
      int row = v * 8 + (l >> 3);
      int col = (l & 7) * 8;
      gload16(posb + (size_t)(i0 + row) * HH + h0 + col, &As[buf][v * 512]);
      gload16(mub + (size_t)row * HH + h0 + col, &Bs[buf][v * 512]);
    }
  };

  stage(0, 0);
  __syncthreads();
  int cur = 0;
  for (int ch = 0; ch < 8; ++ch) {
    if (ch < 7) stage(cur ^ 1, ch + 1);
#pragma unroll
    for (int ks = 0; ks < 2; ++ks) {
      short8v af[4], bfr[4];
      int k = ks * 32 + (l >> 4) * 8;
#pragma unroll
      for (int mi = 0; mi < 4; ++mi) {
        int row = wr * 64 + mi * 16 + (l & 15);
        af[mi] = *(const short8v*)&As[cur][row * 64 + k];
      }
#pragma unroll
      for (int ni = 0; ni < 4; ++ni) {
        int row = wc * 64 + ni * 16 + (l & 15);
        bfr[ni] = *(const short8v*)&Bs[cur][row * 64 + k];
      }
#pragma unroll
      for (int mi = 0; mi < 4; ++mi)
#pragma unroll
        for (int ni = 0; ni < 4; ++ni)
          acc[mi][ni] = __builtin_amdgcn_mfma_f32_16x16x32_bf16(af[mi], bfr[ni], acc[mi][ni], 0, 0, 0);
    }
    __syncthreads();
    cur ^= 1;
  }

  // ---- softmax epilogue. row(local) = wr*64+mi*16+(l>>4)*4+j, col = wc*64+ni*16+(l&15)
  // wave-local row max over its 64 cols
  float wmax[4][4];
#pragma unroll
  for (int mi = 0; mi < 4; ++mi)
#pragma unroll
    for (int j = 0; j < 4; ++j) {
      float m = fmaxf(fmaxf(acc[mi][0][j], acc[mi][1][j]), fmaxf(acc[mi][2][j], acc[mi][3][j])) * BETA;
      m = fmaxf(m, __shfl_xor(m, 1));
      m = fmaxf(m, __shfl_xor(m, 2));
      m = fmaxf(m, __shfl_xor(m, 4));
      m = fmaxf(m, __shfl_xor(m, 8));
      wmax[mi][j] = m;
    }
  if ((l & 15) == 0) {
#pragma unroll
    for (int mi = 0; mi < 4; ++mi)
#pragma unroll
      for (int j = 0; j < 4; ++j)
        redM[wc][wr * 64 + mi * 16 + (l >> 4) * 4 + j] = wmax[mi][j];
  }
  __syncthreads();
  float fm[4][4];
#pragma unroll
  for (int mi = 0; mi < 4; ++mi)
#pragma unroll
    for (int j = 0; j < 4; ++j) {
      int row = wr * 64 + mi * 16 + (l >> 4) * 4 + j;
      fm[mi][j] = fmaxf(redM[0][row], redM[1][row]);
    }
  // exp (in place) + wave-local row sum
#pragma unroll
  for (int mi = 0; mi < 4; ++mi)
#pragma unroll
    for (int j = 0; j < 4; ++j) {
      float s = 0.f;
#pragma unroll
      for (int ni = 0; ni < 4; ++ni) {
        float e = __expf(acc[mi][ni][j] * BETA - fm[mi][j]);
        acc[mi][ni][j] = e;
        s += e;
      }
      s += __shfl_xor(s, 1);
      s += __shfl_xor(s, 2);
      s += __shfl_xor(s, 4);
      s += __shfl_xor(s, 8);
      wmax[mi][j] = s;  // reuse
    }
  if ((l & 15) == 0) {
#pragma unroll
    for (int mi = 0; mi < 4; ++mi)
#pragma unroll
      for (int j = 0; j < 4; ++j)
        redS[wc][wr * 64 + mi * 16 + (l >> 4) * 4 + j] = wmax[mi][j];
  }
  __syncthreads();

  float cpart[4] = {0.f, 0.f, 0.f, 0.f};
#pragma unroll
  for (int mi = 0; mi < 4; ++mi)
#pragma unroll
    for (int j = 0; j < 4; ++j) {
      int row = wr * 64 + mi * 16 + (l >> 4) * 4 + j;
      float invs = 1.0f / (redS[0][row] + redS[1][row]);
      bool valid = (i0 + row) < NN;
#pragma unroll
      for (int ni = 0; ni < 4; ++ni) {
        float rv = acc[mi][ni][j] * invs;
        if (valid) cpart[ni] += rv;
        rT[(wc * 64 + ni * 16 + (l & 15)) * 136 + row] = f2bf(rv);
      }
    }
#pragma unroll
  for (int ni = 0; ni < 4; ++ni) {
    float c = cpart[ni];
    c += __shfl_xor(c, 16);
    c += __shfl_xor(c, 32);
    if (l < 16) atomicAdd(&cluster_r[wc * 64 + ni * 16 + l], c);
  }
  __syncthreads();

  // cooperative global writes from rT
  {
    int c = t >> 1, half = t & 1;
    const unsigned short* src = &rT[c * 136 + half * 64];
    unsigned short* dst = &rbfT[(size_t)c * PADN + i0 + half * 64];
#pragma unroll
    for (int q = 0; q < 8; ++q)
      *(short8v*)(dst + q * 8) = *(const short8v*)(src + q * 8);
  }
  if (write_rbf) {
    int i = t >> 1, chalf = t & 1;
#pragma unroll
    for (int q = 0; q < 8; ++q) {
      short8v v;
#pragma unroll
      for (int e = 0; e < 8; ++e) v[e] = (short)rT[(chalf * 64 + q * 8 + e) * 136 + i];
      *(short8v*)&rbf[(size_t)(i0 + i) * KK + chalf * 64 + q * 8] = v;
    }
  }
}

// ---- MFMA mu update: part[s][c][h] = sum over this split's i of r[i][c]*d[i][h]
__launch_bounds__(256, 2)
__global__ void muup_mfma(const unsigned short* __restrict__ rbfT,
                          const unsigned short* __restrict__ posbT,
                          float* __restrict__ part) {
  __shared__ unsigned short As[2][8192];  // rT tile: [c 128][i 64]
  __shared__ unsigned short Bs[2][8192];  // posT tile: [h 128][i 64]
  int t = threadIdx.x;
  int w = t >> 6, l = t & 63;
  int wr = w >> 1, wc = w & 1;
  int ht = blockIdx.x, s = blockIdx.y;

  float4v acc[4][4];
#pragma unroll
  for (int mi = 0; mi < 4; ++mi)
#pragma unroll
    for (int ni = 0; ni < 4; ++ni) acc[mi][ni] = (float4v){0.f, 0.f, 0.f, 0.f};

  auto stage = [&](int buf, int ch) {
    size_t ib = (size_t)ch * 64;
#pragma unroll
    for (int j = 0; j < 4; ++j) {
      int v = w * 4 + j;
      int row = v * 8 + (l >> 3);
      int col = (l & 7) * 8;
      gload16(rbfT + (size_t)row * PADN + ib + col, &As[buf][v * 512]);
      gload16(posbT + (size_t)(ht * 128 + row) * PADN + ib + col, &Bs[buf][v * 512]);
    }
  };

  int ch = s;
  stage(0, ch);
  __syncthreads();
  int cur = 0;
  for (; ch < NCHUNK; ch += NSPLIT) {
    int nxt = ch + NSPLIT;
    if (nxt < NCHUNK) stage(cur ^ 1, nxt);
#pragma unroll
    for (int ks = 0; ks < 2; ++ks) {
      short8v af[4], bfr[4];
      int k = ks * 32 + (l >> 4) * 8;
#pragma unroll
      for (int mi = 0; mi < 4; ++mi) {
        int row = wr * 64 + mi * 16 + (l & 15);
        af[mi] = *(const short8v*)&As[cur][row * 64 + k];
      }
#pragma unroll
      for (int ni = 0; ni < 4; ++ni) {
        int row = wc * 64 + ni * 16 + (l & 15);
        bfr[ni] = *(const short8v*)&Bs[cur][row * 64 + k];
      }
#pragma unroll
      for (int mi = 0; mi < 4; ++mi)
#pragma unroll
        for (int ni = 0; ni < 4; ++ni)
          acc[mi][ni] = __builtin_amdgcn_mfma_f32_16x16x32_bf16(af[mi], bfr[ni], acc[mi][ni], 0, 0, 0);
    }
    __syncthreads();
    cur ^= 1;
  }
  // write partials: c = wr*64+mi*16+(l>>4)*4+j, hh = wc*64+ni*16+(l&15)
#pragma unroll
  for (int mi = 0; mi < 4; ++mi)
#pragma unroll
    for (int ni = 0; ni < 4; ++ni)
#pragma unroll
      for (int j = 0; j < 4; ++j) {
        int c = wr * 64 + mi * 16 + (l >> 4) * 4 + j;
        int hh = wc * 64 + ni * 16 + (l & 15);
        part[((size_t)s * KK + c) * HH + ht * 128 + hh] = acc[mi][ni][j];
      }
}

// ---- mu[c][h] = (sum_s part[s][c][h]) / cluster_r[c]
__global__ void fin_mu_kernel(const float* __restrict__ part, const float* __restrict__ cluster_r,
                              float* __restrict__ mu) {
  int c = blockIdx.x, t = threadIdx.x;
  float inv = 1.0f / cluster_r[c];
  for (int hh = t; hh < HH; hh += 256) {
    float sum = 0.f;
    for (int s2 = 0; s2 < NSPLIT; ++s2) sum += part[((size_t)s2 * KK + c) * HH + hh];
    mu[c * HH + hh] = sum * inv;
  }
}

// ---- fused loss (round-1 verified structure, r now bf16)
__launch_bounds__(256)
__global__ void loss_kernel(const unsigned short* __restrict__ r_bf, const float* __restrict__ mu,
                            const float* __restrict__ pos, const float* __restrict__ neg,
                            const float* __restrict__ Wsv, float* __restrict__ loss_accum) {
  __shared__ float rS[16][KK];
  __shared__ float pgS[16], ngS[16], pcS[16], ncS[16];
  int t = threadIdx.x;
  int i0 = blockIdx.x * 16;
  int k = t & 127, half = t >> 7;
#pragma unroll
  for (int j = 0; j < 8; ++j) {
    int rr = half + 2 * j;
    rS[rr][k] = bf2f(r_bf[(size_t)(i0 + rr) * KK + k]);
  }
  if (t < 16) {
    pgS[t] = 0.f; ngS[t] = 0.f; pcS[t] = 0.f; ncS[t] = 0.f;
  }
  __syncthreads();
  float w0 = Wsv[t], w1 = Wsv[t + 256];
  float cs0[16], cs1[16];
#pragma unroll
  for (int rr = 0; rr < 16; ++rr) { cs0[rr] = 0.f; cs1[rr] = 0.f; }
  for (int kq = 0; kq < KK; ++kq) {
    float m0 = mu[kq * HH + t];
    float m1 = mu[kq * HH + t + 256];
#pragma unroll
    for (int rr = 0; rr < 16; ++rr) {
      float rv = rS[rr][kq];
      cs0[rr] += rv * m0;
      cs1[rr] += rv * m1;
    }
  }
  int lane = t & 63;
  for (int rr = 0; rr < 16; ++rr) {
    float s0 = 1.0f / (1.0f + expf(-cs0[rr]));
    float s1 = 1.0f / (1.0f + expf(-cs1[rr]));
    const float* pr = pos + (size_t)(i0 + rr) * HH;
    const float* nr = neg + (size_t)(i0 + rr) * HH;
    float p0 = pr[t], p1 = pr[t + 256];
    float n0 = nr[t], n1 = nr[t + 256];
    float pc = p0 * s0 + p1 * s1;
    float nc = n0 * s0 + n1 * s1;
    float pg = p0 * w0 + p1 * w1;
    float ng = n0 * w0 + n1 * w1;
    pc = wave_reduce_sum(pc);
    nc = wave_reduce_sum(nc);
    pg = wave_reduce_sum(pg);
    ng = wave_reduce_sum(ng);
    if (lane == 0) {
      atomicAdd(&pcS[rr], pc);
      atomicAdd(&ncS[rr], nc);
      atomicAdd(&pgS[rr], pg);
      atomicAdd(&ngS[rr], ng);
    }
  }
  __syncthreads();
  if (t < 64) {
    float contrib = 0.f;
    if (t < 16) {
      float pg = pgS[t], ng = ngS[t], pc = pcS[t], nc = ncS[t];
      contrib = 0.5f * (softplusf(-pg) + softplusf(ng)) +
                0.5f * (softplusf(-pc) + softplusf(nc));
    }
    contrib = wave_reduce_sum(contrib);
    if (t == 0) atomicAdd(loss_accum, contrib);
  }
}

__global__ void out_kernel(const float* __restrict__ loss_accum, float* __restrict__ out) {
  out[0] = loss_accum[0] * (1.0f / NN);
}

extern "C" void kernel_launch(void* const* d_in, const int* in_sizes, int n_in,
                              void* d_out, int out_size, void* d_ws, size_t ws_size,
                              hipStream_t stream) {
  const float* pos = (const float*)d_in[0];
  const float* neg = (const float*)d_in[1];
  const float* init = (const float*)d_in[2];
  const float* W = (const float*)d_in[3];
  float* out = (float*)d_out;

  char* ws = (char*)d_ws;
  size_t off = 0;
  auto alloc = [&](size_t bytes) {
    void* p = ws + off;
    off = (off + bytes + 255) & ~(size_t)255;
    return p;
  };
  unsigned short* posb = (unsigned short*)alloc((size_t)PADN * HH * 2);   // 102.5 MB
  unsigned short* posbT = (unsigned short*)alloc((size_t)HH * PADN * 2);  // 102.5 MB
  unsigned short* rbf = (unsigned short*)alloc((size_t)PADN * KK * 2);    // 25.6 MB
  unsigned short* rbfT = (unsigned short*)alloc((size_t)KK * PADN * 2);   // 25.6 MB
  float* part = (float*)alloc((size_t)NSPLIT * KK * HH * 4);              // 33.6 MB
  float* inv_norm = (float*)alloc((size_t)NN * 4);
  float* mu = (float*)alloc((size_t)KK * HH * 4);
  unsigned short* mub = (unsigned short*)alloc((size_t)KK * HH * 2);
  float* cluster_r = (float*)alloc(KK * 4);
  float* colsum = (float*)alloc(HH * 4);
  float* gs = (float*)alloc(HH * 4);
  float* Ws = (float*)alloc(HH * 4);
  float* loss_accum = (float*)alloc(16);

  hipMemsetAsync(colsum, 0, HH * sizeof(float), stream);
  hipMemsetAsync(loss_accum, 0, sizeof(float), stream);
  hipMemcpyAsync(mu, init, (size_t)KK * HH * sizeof(float), hipMemcpyDeviceToDevice, stream);

  prep_kernel<<<256, 256, 0, stream>>>(pos, inv_norm, colsum);
  convert_kernel<<<dim3(PADN / 64, HH / 64), 256, 0, stream>>>(pos, inv_norm, posb, posbT);
  gs_kernel<<<1, 512, 0, stream>>>(colsum, gs);
  wsum_kernel<<<128, 256, 0, stream>>>(W, gs, Ws);

  for (int it = 0; it < ITERS; ++it) {
    norm_mu_kernel<<<KK, 256, 0, stream>>>(mu, mub, cluster_r);
    dist_mfma<<<NBLK, 256, 0, stream>>>(posb, mub, rbf, rbfT, cluster_r, it == ITERS - 1 ? 1 : 0);
    muup_mfma<<<dim3(4, NSPLIT), 256, 0, stream>>>(rbfT, posbT, part);
    fin_mu_kernel<<<KK, 256, 0, stream>>>(part, cluster_r, mu);
  }

  loss_kernel<<<NN / 16, 256, 0, stream>>>(rbf, mu, pos, neg, Ws, loss_accum);
  out_kernel<<<1, 1, 0, stream>>>(loss_accum, out);
}

// Round 3
// 1553.631 us; speedup vs baseline: 6.9905x; 1.1742x over previous
//
#include <hip/hip_runtime.h>
#include <math.h>

#define NN 100000
#define PADN 100096    // 782*128
#define NBLK 782
#define HH 512
#define KK 128
#define BETA 100.0f
#define EPSF 1e-8f
#define ITERS 11
#define NSPLIT 128
#define NCHUNK (PADN / 64)  // 1564

typedef __attribute__((ext_vector_type(8))) short short8v;
typedef __attribute__((ext_vector_type(4))) float float4v;

typedef const __attribute__((address_space(1))) void* gas_t;
typedef __attribute__((address_space(3))) void* las_t;

__device__ __forceinline__ void gload16(const void* g, void* l) {
  __builtin_amdgcn_global_load_lds((gas_t)g, (las_t)l, 16, 0, 0);
}

__device__ __forceinline__ unsigned short f2bf(float x) {
  unsigned int u = __float_as_uint(x);
  unsigned int r = (u + 0x7fff + ((u >> 16) & 1)) >> 16;
  return (unsigned short)r;
}
__device__ __forceinline__ float bf2f(unsigned short b) {
  return __uint_as_float((unsigned int)b << 16);
}

__device__ __forceinline__ float wave_reduce_sum(float v) {
#pragma unroll
  for (int off = 32; off > 0; off >>= 1) v += __shfl_xor(v, off);
  return v;
}
__device__ __forceinline__ float softplusf(float x) {
  return fmaxf(x, 0.0f) + log1pf(expf(-fabsf(x)));
}

// ---- prep: inv_norm[i] = 1/(||pos_i||+eps); colsum[h] = sum_i pos[i][h]
__global__ void prep_kernel(const float* __restrict__ pos,
                            float* __restrict__ inv_norm,
                            float* __restrict__ colsum) {
  int w = threadIdx.x >> 6, lane = threadIdx.x & 63;
  int gw = blockIdx.x * 4 + w;
  float cpart[8] = {0, 0, 0, 0, 0, 0, 0, 0};
  for (int row = gw; row < NN; row += 1024) {
    const float* p = pos + (size_t)row * HH;
    float ss = 0.f;
#pragma unroll
    for (int j = 0; j < 8; ++j) {
      float v = p[lane + 64 * j];
      ss += v * v;
      cpart[j] += v;
    }
    ss = wave_reduce_sum(ss);
    if (lane == 0) inv_norm[row] = 1.0f / (sqrtf(ss) + EPSF);
  }
  __shared__ float cs[HH];
  cs[threadIdx.x] = 0.f;
  cs[threadIdx.x + 256] = 0.f;
  __syncthreads();
#pragma unroll
  for (int j = 0; j < 8; ++j) atomicAdd(&cs[lane + 64 * j], cpart[j]);
  __syncthreads();
  atomicAdd(&colsum[threadIdx.x], cs[threadIdx.x]);
  atomicAdd(&colsum[threadIdx.x + 256], cs[threadIdx.x + 256]);
}

// ---- one-time: normalized bf16 copies of pos: row-major (posb) + transposed (posbT)
__launch_bounds__(256)
__global__ void convert_kernel(const float* __restrict__ pos, const float* __restrict__ inv_norm,
                               unsigned short* __restrict__ posb, unsigned short* __restrict__ posbT) {
  __shared__ unsigned short tile[64][72];
  int t = threadIdx.x;
  int i0 = blockIdx.x * 64, h0 = blockIdx.y * 64;
  int r = t >> 2, cg = (t & 3) * 16;
  int gi = i0 + r;
  bool valid = gi < NN;
  float inv = valid ? inv_norm[gi] : 0.f;
  unsigned short v16[16];
#pragma unroll
  for (int q = 0; q < 4; ++q) {
    float4 f;
    if (valid) f = *(const float4*)&pos[(size_t)gi * HH + h0 + cg + q * 4];
    else { f.x = 0.f; f.y = 0.f; f.z = 0.f; f.w = 0.f; }
    v16[q * 4 + 0] = f2bf(f.x * inv);
    v16[q * 4 + 1] = f2bf(f.y * inv);
    v16[q * 4 + 2] = f2bf(f.z * inv);
    v16[q * 4 + 3] = f2bf(f.w * inv);
  }
#pragma unroll
  for (int q = 0; q < 2; ++q) {
    short8v o;
#pragma unroll
    for (int e = 0; e < 8; ++e) o[e] = (short)v16[q * 8 + e];
    *(short8v*)&posb[(size_t)gi * HH + h0 + cg + q * 8] = o;
  }
#pragma unroll
  for (int q = 0; q < 16; ++q) tile[cg + q][r] = v16[q];
  __syncthreads();
  int h = t >> 2, ig = (t & 3) * 16;
#pragma unroll
  for (int q = 0; q < 2; ++q)
    *(short8v*)&posbT[(size_t)(h0 + h) * PADN + i0 + ig + q * 8] =
        *(const short8v*)&tile[h][ig + q * 8];
}

// ---- gs[h] = sigmoid(colsum[h]/N)
__global__ void gs_kernel(const float* __restrict__ colsum, float* __restrict__ gs) {
  int t = threadIdx.x;
  float m = colsum[t] * (1.0f / NN);
  gs[t] = 1.0f / (1.0f + expf(-m));
}

// ---- Ws[j] = sum_h W[j][h]*gs[h]
__global__ void wsum_kernel(const float* __restrict__ W, const float* __restrict__ gs,
                            float* __restrict__ Ws) {
  int w = threadIdx.x >> 6, lane = threadIdx.x & 63;
  int row = blockIdx.x * 4 + w;
  const float* Wr = W + (size_t)row * HH;
  float s = 0.f;
#pragma unroll
  for (int j = 0; j < 8; ++j) s += Wr[lane + 64 * j] * gs[lane + 64 * j];
  s = wave_reduce_sum(s);
  if (lane == 0) Ws[row] = s;
}

// ---- mu_norm (bf16) = mu / ||mu||; zero cluster_r
__global__ void norm_mu_kernel(const float* __restrict__ mu, unsigned short* __restrict__ mub,
                               float* __restrict__ cluster_r) {
  int k = blockIdx.x, t = threadIdx.x;
  float v0 = mu[k * HH + t], v1 = mu[k * HH + t + 256];
  float ss = v0 * v0 + v1 * v1;
  ss = wave_reduce_sum(ss);
  __shared__ float red[4];
  if ((t & 63) == 0) red[t >> 6] = ss;
  __syncthreads();
  float inv = 1.0f / sqrtf(red[0] + red[1] + red[2] + red[3]);
  mub[k * HH + t] = f2bf(v0 * inv);
  mub[k * HH + t + 256] = f2bf(v1 * inv);
  if (t == 0) cluster_r[k] = 0.f;
}

// ---- MFMA dist + fused softmax: writes rbfT (always), rbf (flag), cluster_r (fp32 exact)
__launch_bounds__(256, 2)
__global__ void dist_mfma(const unsigned short* __restrict__ posb,
                          const unsigned short* __restrict__ mub,
                          unsigned short* __restrict__ rbf,
                          unsigned short* __restrict__ rbfT,
                          float* __restrict__ cluster_r,
                          int write_rbf) {
  __shared__ unsigned short As[2][8192];  // [row 128][col 64] bf16
  __shared__ unsigned short Bs[2][8192];
  __shared__ float redM[2][128];
  __shared__ float redS[2][128];
  unsigned short* rT = (unsigned short*)&As[0][0];  // [128 c][136] aliased in epilogue

  int t = threadIdx.x;
  int w = t >> 6, l = t & 63;
  int wr = w >> 1, wc = w & 1;
  int i0 = blockIdx.x * 128;

  float4v acc[4][4];
#pragma unroll
  for (int mi = 0; mi < 4; ++mi)
#pragma unroll
    for (int ni = 0; ni < 4; ++ni) acc[mi][ni] = (float4v){0.f, 0.f, 0.f, 0.f};

  auto stage = [&](int buf, int ch) {
    int h0 = ch * 64;
#pragma unroll
    for (int j = 0; j < 4; ++j) {
      int v = w * 4 + j;
      int row = v * 8 + (l >> 3);
      int col = (l & 7) * 8;
      gload16(posb + (size_t)(i0 + row) * HH + h0 + col, &As[buf][v * 512]);
      gload16(mub + (size_t)row * HH + h0 + col, &Bs[buf][v * 512]);
    }
  };

  stage(0, 0);
  __syncthreads();
  int cur = 0;
  for (int ch = 0; ch < 8; ++ch) {
    if (ch < 7) stage(cur ^ 1, ch + 1);
#pragma unroll
    for (int ks = 0; ks < 2; ++ks) {
      short8v af[4], bfr[4];
      int k = ks * 32 + (l >> 4) * 8;
#pragma unroll
      for (int mi = 0; mi < 4; ++mi) {
        int row = wr * 64 + mi * 16 + (l & 15);
        af[mi] = *(const short8v*)&As[cur][row * 64 + k];
      }
#pragma unroll
      for (int ni = 0; ni < 4; ++ni) {
        int row = wc * 64 + ni * 16 + (l & 15);
        bfr[ni] = *(const short8v*)&Bs[cur][row * 64 + k];
      }
#pragma unroll
      for (int mi = 0; mi < 4; ++mi)
#pragma unroll
        for (int ni = 0; ni < 4; ++ni)
          acc[mi][ni] = __builtin_amdgcn_mfma_f32_16x16x32_bf16(af[mi], bfr[ni], acc[mi][ni], 0, 0, 0);
    }
    __syncthreads();
    cur ^= 1;
  }

  // ---- softmax epilogue. row(local) = wr*64+mi*16+(l>>4)*4+j, col = wc*64+ni*16+(l&15)
  float wmax[4][4];
#pragma unroll
  for (int mi = 0; mi < 4; ++mi)
#pragma unroll
    for (int j = 0; j < 4; ++j) {
      float m = fmaxf(fmaxf(acc[mi][0][j], acc[mi][1][j]), fmaxf(acc[mi][2][j], acc[mi][3][j])) * BETA;
      m = fmaxf(m, __shfl_xor(m, 1));
      m = fmaxf(m, __shfl_xor(m, 2));
      m = fmaxf(m, __shfl_xor(m, 4));
      m = fmaxf(m, __shfl_xor(m, 8));
      wmax[mi][j] = m;
    }
  if ((l & 15) == 0) {
#pragma unroll
    for (int mi = 0; mi < 4; ++mi)
#pragma unroll
      for (int j = 0; j < 4; ++j)
        redM[wc][wr * 64 + mi * 16 + (l >> 4) * 4 + j] = wmax[mi][j];
  }
  __syncthreads();
  float fm[4][4];
#pragma unroll
  for (int mi = 0; mi < 4; ++mi)
#pragma unroll
    for (int j = 0; j < 4; ++j) {
      int row = wr * 64 + mi * 16 + (l >> 4) * 4 + j;
      fm[mi][j] = fmaxf(redM[0][row], redM[1][row]);
    }
#pragma unroll
  for (int mi = 0; mi < 4; ++mi)
#pragma unroll
    for (int j = 0; j < 4; ++j) {
      float s = 0.f;
#pragma unroll
      for (int ni = 0; ni < 4; ++ni) {
        float e = __expf(acc[mi][ni][j] * BETA - fm[mi][j]);
        acc[mi][ni][j] = e;
        s += e;
      }
      s += __shfl_xor(s, 1);
      s += __shfl_xor(s, 2);
      s += __shfl_xor(s, 4);
      s += __shfl_xor(s, 8);
      wmax[mi][j] = s;  // reuse
    }
  if ((l & 15) == 0) {
#pragma unroll
    for (int mi = 0; mi < 4; ++mi)
#pragma unroll
      for (int j = 0; j < 4; ++j)
        redS[wc][wr * 64 + mi * 16 + (l >> 4) * 4 + j] = wmax[mi][j];
  }
  __syncthreads();

  float cpart[4] = {0.f, 0.f, 0.f, 0.f};
#pragma unroll
  for (int mi = 0; mi < 4; ++mi)
#pragma unroll
    for (int j = 0; j < 4; ++j) {
      int row = wr * 64 + mi * 16 + (l >> 4) * 4 + j;
      float invs = 1.0f / (redS[0][row] + redS[1][row]);
      bool valid = (i0 + row) < NN;
#pragma unroll
      for (int ni = 0; ni < 4; ++ni) {
        float rv = acc[mi][ni][j] * invs;
        if (valid) cpart[ni] += rv;
        rT[(wc * 64 + ni * 16 + (l & 15)) * 136 + row] = f2bf(rv);
      }
    }
#pragma unroll
  for (int ni = 0; ni < 4; ++ni) {
    float c = cpart[ni];
    c += __shfl_xor(c, 16);
    c += __shfl_xor(c, 32);
    if (l < 16) atomicAdd(&cluster_r[wc * 64 + ni * 16 + l], c);
  }
  __syncthreads();

  {
    int c = t >> 1, half = t & 1;
    const unsigned short* src = &rT[c * 136 + half * 64];
    unsigned short* dst = &rbfT[(size_t)c * PADN + i0 + half * 64];
#pragma unroll
    for (int q = 0; q < 8; ++q)
      *(short8v*)(dst + q * 8) = *(const short8v*)(src + q * 8);
  }
  if (write_rbf) {
    int i = t >> 1, chalf = t & 1;
#pragma unroll
    for (int q = 0; q < 8; ++q) {
      short8v v;
#pragma unroll
      for (int e = 0; e < 8; ++e) v[e] = (short)rT[(chalf * 64 + q * 8 + e) * 136 + i];
      *(short8v*)&rbf[(size_t)(i0 + i) * KK + chalf * 64 + q * 8] = v;
    }
  }
}

// ---- MFMA mu update: part[s][c][h] (bf16) = sum over this split's i of r[i][c]*d[i][h]
__launch_bounds__(256, 2)
__global__ void muup_mfma(const unsigned short* __restrict__ rbfT,
                          const unsigned short* __restrict__ posbT,
                          unsigned short* __restrict__ part) {
  __shared__ unsigned short As[2][8192];  // rT tile: [c 128][i 64]
  __shared__ unsigned short Bs[2][8192];  // posT tile: [h 128][i 64]
  int t = threadIdx.x;
  int w = t >> 6, l = t & 63;
  int wr = w >> 1, wc = w & 1;
  int ht = blockIdx.x, s = blockIdx.y;

  float4v acc[4][4];
#pragma unroll
  for (int mi = 0; mi < 4; ++mi)
#pragma unroll
    for (int ni = 0; ni < 4; ++ni) acc[mi][ni] = (float4v){0.f, 0.f, 0.f, 0.f};

  auto stage = [&](int buf, int ch) {
    size_t ib = (size_t)ch * 64;
#pragma unroll
    for (int j = 0; j < 4; ++j) {
      int v = w * 4 + j;
      int row = v * 8 + (l >> 3);
      int col = (l & 7) * 8;
      gload16(rbfT + (size_t)row * PADN + ib + col, &As[buf][v * 512]);
      gload16(posbT + (size_t)(ht * 128 + row) * PADN + ib + col, &Bs[buf][v * 512]);
    }
  };

  int ch = s;
  stage(0, ch);
  __syncthreads();
  int cur = 0;
  for (; ch < NCHUNK; ch += NSPLIT) {
    int nxt = ch + NSPLIT;
    if (nxt < NCHUNK) stage(cur ^ 1, nxt);
#pragma unroll
    for (int ks = 0; ks < 2; ++ks) {
      short8v af[4], bfr[4];
      int k = ks * 32 + (l >> 4) * 8;
#pragma unroll
      for (int mi = 0; mi < 4; ++mi) {
        int row = wr * 64 + mi * 16 + (l & 15);
        af[mi] = *(const short8v*)&As[cur][row * 64 + k];
      }
#pragma unroll
      for (int ni = 0; ni < 4; ++ni) {
        int row = wc * 64 + ni * 16 + (l & 15);
        bfr[ni] = *(const short8v*)&Bs[cur][row * 64 + k];
      }
#pragma unroll
      for (int mi = 0; mi < 4; ++mi)
#pragma unroll
        for (int ni = 0; ni < 4; ++ni)
          acc[mi][ni] = __builtin_amdgcn_mfma_f32_16x16x32_bf16(af[mi], bfr[ni], acc[mi][ni], 0, 0, 0);
    }
    __syncthreads();
    cur ^= 1;
  }
#pragma unroll
  for (int mi = 0; mi < 4; ++mi)
#pragma unroll
    for (int ni = 0; ni < 4; ++ni)
#pragma unroll
      for (int j = 0; j < 4; ++j) {
        int c = wr * 64 + mi * 16 + (l >> 4) * 4 + j;
        int hh = wc * 64 + ni * 16 + (l & 15);
        part[((size_t)s * KK + c) * HH + ht * 128 + hh] = f2bf(acc[mi][ni][j]);
      }
}

// ---- mu[c][h] = (sum_s part[s][c][h]) / cluster_r[c]; also mubT bf16 [h][k]
__global__ void fin_mu_kernel(const unsigned short* __restrict__ part,
                              const float* __restrict__ cluster_r,
                              float* __restrict__ mu, unsigned short* __restrict__ mubT) {
  int o = blockIdx.x * 256 + threadIdx.x;  // 65536 outputs
  int c = o >> 9, hh = o & 511;
  float inv = 1.0f / cluster_r[c];
  float sum = 0.f;
#pragma unroll 8
  for (int s2 = 0; s2 < NSPLIT; ++s2) sum += bf2f(part[((size_t)s2 * KK + c) * HH + hh]);
  float v = sum * inv;
  mu[o] = v;
  mubT[(size_t)hh * KK + c] = f2bf(v);
}

// ---- MFMA loss: cs = sigmoid(r@mu) via MFMA, fused dots with pos/neg/Ws, softplus reduce.
// 512 threads = 8 waves, wave grid 4(rows)x2(cols of 64h), tile 128 rows x 128 h per pass, 4 passes.
__launch_bounds__(512, 2)
__global__ void loss_mfma(const unsigned short* __restrict__ rbf,
                          const unsigned short* __restrict__ mubT,
                          const float* __restrict__ pos, const float* __restrict__ neg,
                          const float* __restrict__ Wsv, float* __restrict__ loss_accum) {
  __shared__ unsigned short rS[128 * 128];  // 32KB [i][k], XOR-swizzled
  __shared__ unsigned short BsL[128 * 128]; // 32KB [h][k] per pass, XOR-swizzled
  __shared__ float pcS[2][128], ncS[2][128], pgS[2][128], ngS[2][128];
  __shared__ float WsS[HH];
  int t = threadIdx.x;
  int w = t >> 6, l = t & 63;
  int wr = w >> 1, wc = w & 1;
  int i0 = blockIdx.x * 128;

  // stage rS once: slot(v,l) = LDS byte v*1024+16l -> row=v*4+(l>>4), src col swizzled
  {
    const char* gb = (const char*)rbf + (size_t)i0 * KK * 2;
#pragma unroll
    for (int j = 0; j < 4; ++j) {
      int v = w * 4 + j;
      int row = v * 4 + (l >> 4);
      int cb = ((l & 15) * 16) ^ ((row & 7) << 4);
      gload16(gb + (size_t)row * 256 + cb, (char*)rS + v * 1024);
    }
  }
  if (t < HH) WsS[t] = Wsv[t];
  if (t < 256) {
    pcS[t >> 7][t & 127] = 0.f;
    ncS[t >> 7][t & 127] = 0.f;
    pgS[t >> 7][t & 127] = 0.f;
    ngS[t >> 7][t & 127] = 0.f;
  }

  for (int p = 0; p < 4; ++p) {
    __syncthreads();  // previous pass done with BsL (and init/rS barrier on p=0)
    {
      const char* gb = (const char*)mubT + (size_t)p * 128 * 256;
#pragma unroll
      for (int j = 0; j < 4; ++j) {
        int v = w * 4 + j;
        int row = v * 4 + (l >> 4);
        int cb = ((l & 15) * 16) ^ ((row & 7) << 4);
        gload16(gb + (size_t)row * 256 + cb, (char*)BsL + v * 1024);
      }
    }
    __syncthreads();  // BsL ready (vmcnt drained)

    float4v acc[2][4];
#pragma unroll
    for (int mi = 0; mi < 2; ++mi)
#pragma unroll
      for (int ni = 0; ni < 4; ++ni) acc[mi][ni] = (float4v){0.f, 0.f, 0.f, 0.f};

#pragma unroll
    for (int ks = 0; ks < 4; ++ks) {
      short8v af[2], bfr[4];
      int kb = ks * 64 + (l >> 4) * 16;
#pragma unroll
      for (int mi = 0; mi < 2; ++mi) {
        int row = wr * 32 + mi * 16 + (l & 15);
        af[mi] = *(const short8v*)((const char*)rS + row * 256 + (kb ^ ((row & 7) << 4)));
      }
#pragma unroll
      for (int ni = 0; ni < 4; ++ni) {
        int hrow = wc * 64 + ni * 16 + (l & 15);
        bfr[ni] = *(const short8v*)((const char*)BsL + hrow * 256 + (kb ^ ((hrow & 7) << 4)));
      }
#pragma unroll
      for (int mi = 0; mi < 2; ++mi)
#pragma unroll
        for (int ni = 0; ni < 4; ++ni)
          acc[mi][ni] = __builtin_amdgcn_mfma_f32_16x16x32_bf16(af[mi], bfr[ni], acc[mi][ni], 0, 0, 0);
    }

    // dot phase: cell (row, col) col_local = wc*64+ni*16+(l&15), h = p*128+col_local
    float wsv4[4];
#pragma unroll
    for (int ni = 0; ni < 4; ++ni) wsv4[ni] = WsS[p * 128 + wc * 64 + ni * 16 + (l & 15)];

#pragma unroll
    for (int mi = 0; mi < 2; ++mi)
#pragma unroll
      for (int j = 0; j < 4; ++j) {
        int row = wr * 32 + mi * 16 + (l >> 4) * 4 + j;
        int gi = i0 + row;
        bool valid = gi < NN;
        const float* pr = pos + (size_t)gi * HH + p * 128;
        const float* nr = neg + (size_t)gi * HH + p * 128;
        float pc = 0.f, nc = 0.f, pg = 0.f, ng = 0.f;
#pragma unroll
        for (int ni = 0; ni < 4; ++ni) {
          int col = wc * 64 + ni * 16 + (l & 15);
          float s = 1.0f / (1.0f + __expf(-acc[mi][ni][j]));
          float pv = valid ? pr[col] : 0.f;
          float nv = valid ? nr[col] : 0.f;
          pc += s * pv;
          nc += s * nv;
          pg += wsv4[ni] * pv;
          ng += wsv4[ni] * nv;
        }
#pragma unroll
        for (int o = 1; o < 16; o <<= 1) {
          pc += __shfl_xor(pc, o);
          nc += __shfl_xor(nc, o);
          pg += __shfl_xor(pg, o);
          ng += __shfl_xor(ng, o);
        }
        if ((l & 15) == 0) {
          pcS[wc][row] += pc;
          ncS[wc][row] += nc;
          pgS[wc][row] += pg;
          ngS[wc][row] += ng;
        }
      }
  }
  __syncthreads();
  if (t < 128) {
    int gi = i0 + t;
    float contrib = 0.f;
    if (gi < NN) {
      float pg = pgS[0][t] + pgS[1][t];
      float ng = ngS[0][t] + ngS[1][t];
      float pc = pcS[0][t] + pcS[1][t];
      float nc = ncS[0][t] + ncS[1][t];
      contrib = 0.5f * (softplusf(-pg) + softplusf(ng)) +
                0.5f * (softplusf(-pc) + softplusf(nc));
    }
    contrib = wave_reduce_sum(contrib);
    if (l == 0) atomicAdd(loss_accum, contrib);
  }
}

__global__ void out_kernel(const float* __restrict__ loss_accum, float* __restrict__ out) {
  out[0] = loss_accum[0] * (1.0f / NN);
}

extern "C" void kernel_launch(void* const* d_in, const int* in_sizes, int n_in,
                              void* d_out, int out_size, void* d_ws, size_t ws_size,
                              hipStream_t stream) {
  const float* pos = (const float*)d_in[0];
  const float* neg = (const float*)d_in[1];
  const float* init = (const float*)d_in[2];
  const float* W = (const float*)d_in[3];
  float* out = (float*)d_out;

  char* ws = (char*)d_ws;
  size_t off = 0;
  auto alloc = [&](size_t bytes) {
    void* p = ws + off;
    off = (off + bytes + 255) & ~(size_t)255;
    return p;
  };
  unsigned short* posb = (unsigned short*)alloc((size_t)PADN * HH * 2);   // 102.5 MB
  unsigned short* posbT = (unsigned short*)alloc((size_t)HH * PADN * 2);  // 102.5 MB
  unsigned short* rbf = (unsigned short*)alloc((size_t)PADN * KK * 2);    // 25.6 MB
  unsigned short* rbfT = (unsigned short*)alloc((size_t)KK * PADN * 2);   // 25.6 MB
  unsigned short* part = (unsigned short*)alloc((size_t)NSPLIT * KK * HH * 2);  // 16.8 MB
  float* inv_norm = (float*)alloc((size_t)NN * 4);
  float* mu = (float*)alloc((size_t)KK * HH * 4);
  unsigned short* mub = (unsigned short*)alloc((size_t)KK * HH * 2);
  unsigned short* mubT = (unsigned short*)alloc((size_t)KK * HH * 2);
  float* cluster_r = (float*)alloc(KK * 4);
  float* colsum = (float*)alloc(HH * 4);
  float* gs = (float*)alloc(HH * 4);
  float* Ws = (float*)alloc(HH * 4);
  float* loss_accum = (float*)alloc(16);

  hipMemsetAsync(colsum, 0, HH * sizeof(float), stream);
  hipMemsetAsync(loss_accum, 0, sizeof(float), stream);
  hipMemcpyAsync(mu, init, (size_t)KK * HH * sizeof(float), hipMemcpyDeviceToDevice, stream);

  prep_kernel<<<256, 256, 0, stream>>>(pos, inv_norm, colsum);
  convert_kernel<<<dim3(PADN / 64, HH / 64), 256, 0, stream>>>(pos, inv_norm, posb, posbT);
  gs_kernel<<<1, 512, 0, stream>>>(colsum, gs);
  wsum_kernel<<<128, 256, 0, stream>>>(W, gs, Ws);

  for (int it = 0; it < ITERS; ++it) {
    norm_mu_kernel<<<KK, 256, 0, stream>>>(mu, mub, cluster_r);
    dist_mfma<<<NBLK, 256, 0, stream>>>(posb, mub, rbf, rbfT, cluster_r, it == ITERS - 1 ? 1 : 0);
    muup_mfma<<<dim3(4, NSPLIT), 256, 0, stream>>>(rbfT, posbT, part);
    fin_mu_kernel<<<KK * HH / 256, 256, 0, stream>>>(part, cluster_r, mu, mubT);
  }

  loss_mfma<<<NBLK, 512, 0, stream>>>(rbf, mubT, pos, neg, Ws, loss_accum);
  out_kernel<<<1, 1, 0, stream>>>(loss_accum, out);
}